// Round 15
// baseline (10752.699 us; speedup 1.0000x reference)
//
#include <hip/hip_runtime.h>
#include <cstdint>
#include <cstddef>

#define T_N 1024
#define B_N 64
#define I_N 512
#define H_N 512
#define G3  (3*H_N)

typedef _Float16 f16;
typedef _Float16 f16x2 __attribute__((ext_vector_type(2)));
typedef unsigned long long ull;

// 8-deep exchange ring: generation d -> slot S8(d), LSB tag T8(d).
// T8(-1)=0 matches pack_h_init. Replay-safe: leftover gen d+1016 has flipped
// tag (127 odd); the d=-1 vs 1023 alias (same slot+tag) is re-inited by pack.
#define S8(d) (((d)+8)&7)
#define T8(d) ((((d)+8)>>3)&1)

__device__ __forceinline__ f16x2 mkh2(float a, float b) {
  f16x2 v; v.x = (_Float16)a; v.y = (_Float16)b; return v;
}
__device__ __forceinline__ f16x2 bch2(unsigned int u) {
  return __builtin_bit_cast(f16x2, u);
}
__device__ __forceinline__ float fdot2_(f16x2 a, f16x2 b, float c) {
#if __has_builtin(__builtin_amdgcn_fdot2)
  return __builtin_amdgcn_fdot2(a, b, c, false);
#else
  return fmaf((float)a.x, (float)b.x, fmaf((float)a.y, (float)b.y, c));
#endif
}
__device__ __forceinline__ float sigm_(float x) { return 1.f / (1.f + __expf(-x)); }
__device__ __forceinline__ float tanhf_(float x) {
  float xx = fminf(15.f, fmaxf(-15.f, x));
  float e = __expf(2.f * xx);
  return (e - 1.f) / (e + 1.f);
}

// ---------------------------------------------------------------------------
// GEMM: C[m][n] = sum_k A[m][k]*W[n][k] + bias[n]   (layer-0 input gates)
// ---------------------------------------------------------------------------
__global__ __launch_bounds__(256) void gemm_nt(
    const float* __restrict__ A,
    const float* __restrict__ W,
    const float* __restrict__ bias,
    float* __restrict__ C,
    int M, int N, int K)
{
  __shared__ float As[32][68];
  __shared__ float Ws[32][68];
  const int tid = threadIdx.x;
  const int n0 = blockIdx.x * 64;
  const int m0 = blockIdx.y * 64;
  const int ty = tid >> 4;
  const int tx = tid & 15;

  float acc[4][4];
#pragma unroll
  for (int i = 0; i < 4; ++i)
#pragma unroll
    for (int jj = 0; jj < 4; ++jj) acc[i][jj] = 0.f;

  for (int k0 = 0; k0 < K; k0 += 32) {
#pragma unroll
    for (int i = 0; i < 2; ++i) {
      int idx = tid + i * 256;
      int r   = idx >> 3;
      int c4  = idx & 7;
      float4 va = *(const float4*)(A + (size_t)(m0 + r) * K + k0 + c4 * 4);
      As[c4*4+0][r] = va.x; As[c4*4+1][r] = va.y;
      As[c4*4+2][r] = va.z; As[c4*4+3][r] = va.w;
      float4 vw = *(const float4*)(W + (size_t)(n0 + r) * K + k0 + c4 * 4);
      Ws[c4*4+0][r] = vw.x; Ws[c4*4+1][r] = vw.y;
      Ws[c4*4+2][r] = vw.z; Ws[c4*4+3][r] = vw.w;
    }
    __syncthreads();
#pragma unroll
    for (int k = 0; k < 32; ++k) {
      float4 a = *(const float4*)&As[k][ty * 4];
      float4 w = *(const float4*)&Ws[k][tx * 4];
      acc[0][0] += a.x*w.x; acc[0][1] += a.x*w.y; acc[0][2] += a.x*w.z; acc[0][3] += a.x*w.w;
      acc[1][0] += a.y*w.x; acc[1][1] += a.y*w.y; acc[1][2] += a.y*w.z; acc[1][3] += a.y*w.w;
      acc[2][0] += a.z*w.x; acc[2][1] += a.z*w.y; acc[2][2] += a.z*w.z; acc[2][3] += a.z*w.w;
      acc[3][0] += a.w*w.x; acc[3][1] += a.w*w.y; acc[3][2] += a.w*w.z; acc[3][3] += a.w*w.w;
    }
    __syncthreads();
  }

  float4 bv = *(const float4*)(bias + n0 + tx * 4);
#pragma unroll
  for (int i = 0; i < 4; ++i) {
    int row = m0 + ty * 4 + i;
    float4 o;
    o.x = acc[i][0] + bv.x; o.y = acc[i][1] + bv.y;
    o.z = acc[i][2] + bv.z; o.w = acc[i][3] + bv.w;
    *(float4*)(C + (size_t)row * N + n0 + tx * 4) = o;
  }
}

// init: pack fp32 hx -> f16 ring slot S8(-1)=7 with tag T8(-1)=0 (LSB clear)
__global__ __launch_bounds__(256) void pack_h_init(
    const float* __restrict__ hx, f16* __restrict__ h0x, f16* __restrict__ h1x)
{
  int i = blockIdx.x * 256 + threadIdx.x;   // 0..32767
  unsigned short a = __builtin_bit_cast(unsigned short, (f16)hx[i]) & 0xFFFEu;
  unsigned short b = __builtin_bit_cast(unsigned short, (f16)hx[B_N * H_N + i]) & 0xFFFEu;
  ((unsigned short*)h0x)[7 * B_N * H_N + i] = a;
  ((unsigned short*)h1x)[7 * B_N * H_N + i] = b;
}

// ---------------------------------------------------------------------------
// conv_w: pre-convert weights to f16, per-(j,tid256) layout:
// wbuf[(j*256+tid)*36 + idx], idx=(mat*3+q)*4+c; uint4 = 8 halfs at
// k = 8*s + 128*c (thread u=tid>>4, s=tid&15). mat: 0=whh0, 1=wih1, 2=whh1.
// ---------------------------------------------------------------------------
__global__ __launch_bounds__(256) void conv_w(
    const float* __restrict__ whh0, const float* __restrict__ wih1,
    const float* __restrict__ whh1, uint4* __restrict__ wbuf)
{
  int gid = blockIdx.x * 256 + threadIdx.x;        // 0..294911
  int idx = gid % 36, rem = gid / 36;
  int tid = rem % 256, j = rem / 256;
  int u = tid >> 4, s = tid & 15;
  int mat = idx / 12, q = (idx % 12) / 4, c = idx % 4;
  const float* src = mat == 0 ? whh0 : (mat == 1 ? wih1 : whh1);
  const float* p = src + (size_t)(q * H_N + 16 * j + u) * H_N + 8 * s + 128 * c;
  uint4 o;
  o.x = __builtin_bit_cast(unsigned int, mkh2(p[0], p[1]));
  o.y = __builtin_bit_cast(unsigned int, mkh2(p[2], p[3]));
  o.z = __builtin_bit_cast(unsigned int, mkh2(p[4], p[5]));
  o.w = __builtin_bit_cast(unsigned int, mkh2(p[6], p[7]));
  wbuf[gid] = o;
}

#define D4Q(acc, wv, vv)                               \
  acc = fdot2_(bch2((wv).x), bch2((vv).x), acc);       \
  acc = fdot2_(bch2((wv).y), bch2((vv).y), acc);       \
  acc = fdot2_(bch2((wv).z), bch2((vv).z), acc);       \
  acc = fdot2_(bch2((wv).w), bch2((vv).w), acc);

// reduce-scatter 8 accumulators over the 16-lane s-group.
// After: every lane holds the full sum for bb = 4(s&1)+2((s>>1)&1)+((s>>2)&1).
template <int NQ>
__device__ __forceinline__ void rscat8(float a[][8], float* r, int s) {
#pragma unroll
  for (int q = 0; q < NQ; ++q) {
    float k4[4];
#pragma unroll
    for (int i = 0; i < 4; ++i) {
      float snd = (s & 1) ? a[q][i] : a[q][4 + i];
      float kp  = (s & 1) ? a[q][4 + i] : a[q][i];
      k4[i] = kp + __shfl_xor(snd, 1);
    }
    float k2[2];
#pragma unroll
    for (int i = 0; i < 2; ++i) {
      float snd = (s & 2) ? k4[i] : k4[2 + i];
      float kp  = (s & 2) ? k4[2 + i] : k4[i];
      k2[i] = kp + __shfl_xor(snd, 2);
    }
    float snd = (s & 4) ? k2[0] : k2[1];
    float kp  = (s & 4) ? k2[1] : k2[0];
    float k1 = kp + __shfl_xor(snd, 4);
    r[q] = k1 + __shfl_xor(k1, 8);
  }
}

#define POLL4(vv, kk, sp, ee)                                                  \
  for (;;) {                                                                   \
    bool all_ = true;                                                          \
    _Pragma("unroll")                                                          \
    for (int e_ = 0; e_ < 4; ++e_) {                                           \
      if (!kk[e_]) kk[e_] = ((vv[e_] & M) == ee);                              \
      all_ = all_ && kk[e_];                                                   \
    }                                                                          \
    if (__all(all_)) break;                                                    \
    __builtin_amdgcn_s_sleep(1);                                               \
    _Pragma("unroll")                                                          \
    for (int e_ = 0; e_ < 4; ++e_)                                             \
      if (!kk[e_]) vv[e_] = __hip_atomic_load(sp + e_ * 256 + tid,             \
                     __ATOMIC_RELAXED, __HIP_MEMORY_SCOPE_AGENT);              \
  }

// ---------------------------------------------------------------------------
// Decoupled-layer persistent scan: 512 blocks (2/CU). bid<256: LAYER 0 only
// (the latency-critical chain: poll h0_{t-1} -> 384 dot2 -> store h0_t).
// bid>=256: LAYER 1 only, trailing asynchronously (polls hit stale=ready
// data; its waves fill layer-0's poll stalls on the same CU). 8-deep tagged
// rings let layer 1 lag <=7 steps; layer 0 throttles on h1_{t-7} (always
// stale -> instant) before overwriting ring slot t&7.
// ---------------------------------------------------------------------------
__global__ __launch_bounds__(256) void gru_split(
    const float* __restrict__ gx,    // [T][64][1536] layer-0 input gates
    const float* __restrict__ hx,    // [2][64][512] fp32 initial h
    const uint4* __restrict__ wbuf,  // pre-converted f16 weights
    const float* __restrict__ bih1, const float* __restrict__ bhh0,
    const float* __restrict__ bhh1,
    float* __restrict__ out,         // [T][64][512]
    float* __restrict__ hT,          // [2][64][512]
    f16* __restrict__ h0x, f16* __restrict__ h1x)  // 8-slot tagged rings
{
  __shared__ __align__(16) ull shq[1024];       // 8 KB staged h0
  __shared__ __align__(16) ull sh1q[1024];      // 8 KB staged h1 (L1 only)
  __shared__ __align__(8) unsigned short pk[128];

  const int tid = threadIdx.x;
  const bool L0 = (blockIdx.x < 256);
  const int lb = L0 ? blockIdx.x : blockIdx.x - 256;
  const int g = lb & 7;         // batch group (8 batches)
  const int j = lb >> 3;        // units 16j..16j+15
  const int u = tid >> 4;       // unit 0..15
  const int s = tid & 15;       // k-split 0..15
  const ull M = 0x0001000100010001ULL;

  const int bb   = 4 * (s & 1) + 2 * ((s >> 1) & 1) + ((s >> 2) & 1);
  const int unit = 16 * j + u;
  const int gbi  = 8 * g + bb;
  const bool wr  = (s < 8);
  const ull* h0u = (const ull*)h0x;
  const ull* h1u = (const ull*)h1x;

  if (L0) {
    // ---- layer 0: whh0 slice, 12 uint4 in registers (fits RA budget) ----
    uint4 wq[12];
    {
      const uint4* wp = wbuf + ((size_t)j * 256 + tid) * 36;
#pragma unroll
      for (int i = 0; i < 12; ++i) wq[i] = wp[i];
#pragma unroll
      for (int i = 0; i < 12; ++i)
        asm volatile("" : "+v"(wq[i].x), "+v"(wq[i].y), "+v"(wq[i].z), "+v"(wq[i].w));
    }
    float bR0 = 0, bZ0 = 0, bN0 = 0, hv0 = 0;
    if (wr) {
      bR0 = bhh0[unit]; bZ0 = bhh0[H_N + unit]; bN0 = bhh0[2 * H_N + unit];
      hv0 = hx[(size_t)gbi * H_N + unit];
    }

    for (int t = 0; t < T_N; ++t) {
      // fire h0_{t-1} data loads + h1_{t-7} throttle loads
      const ull* s0 = h0u + (size_t)S8(t - 1) * 8192 + (size_t)(8 * g) * 128;
      const ull e0 = T8(t - 1) ? M : 0ULL;
      ull v0[4]; bool k0[4] = {false, false, false, false};
#pragma unroll
      for (int e = 0; e < 4; ++e)
        v0[e] = __hip_atomic_load(s0 + e * 256 + tid, __ATOMIC_RELAXED, __HIP_MEMORY_SCOPE_AGENT);
      const bool thr = (t >= 7);
      const ull* sT = h1u + (size_t)S8(t - 7) * 8192 + (size_t)(8 * g) * 128;
      const ull eT = T8(t - 7) ? M : 0ULL;
      ull vT[4]; bool kT[4] = {!thr, !thr, !thr, !thr};
      if (thr) {
#pragma unroll
        for (int e = 0; e < 4; ++e)
          vT[e] = __hip_atomic_load(sT + e * 256 + tid, __ATOMIC_RELAXED, __HIP_MEMORY_SCOPE_AGENT);
      }
      float ir0 = 0, iz0 = 0, in0 = 0;
      if (wr) {
        const float* p = gx + ((size_t)t * B_N + gbi) * G3 + unit;
        ir0 = p[0]; iz0 = p[H_N]; in0 = p[2 * H_N];
      }

      POLL4(v0, k0, s0, e0)
#pragma unroll
      for (int e = 0; e < 4; ++e) shq[e * 256 + tid] = v0[e];
      __syncthreads();

      // A compute: 3 gates x 8 batches, register weights
      float aA[3][8];
#pragma unroll
      for (int q = 0; q < 3; ++q)
#pragma unroll
        for (int b8 = 0; b8 < 8; ++b8) aA[q][b8] = 0.f;
      const uint4* xp = (const uint4*)shq;
#pragma unroll
      for (int b8 = 0; b8 < 8; ++b8) {
        uint4 xc[4];
#pragma unroll
        for (int c = 0; c < 4; ++c) xc[c] = xp[b8 * 64 + s + 16 * c];
        float a0 = aA[0][b8], a1 = aA[1][b8], a2 = aA[2][b8];
#pragma unroll
        for (int c = 0; c < 4; ++c) {
          D4Q(a0, wq[0 + c], xc[c]);
          D4Q(a1, wq[4 + c], xc[c]);
          D4Q(a2, wq[8 + c], xc[c]);
        }
        aA[0][b8] = a0; aA[1][b8] = a1; aA[2][b8] = a2;
      }
      float rA[3];
      rscat8<3>(aA, rA, s);
      if (wr) {
        float r = sigm_(ir0 + rA[0] + bR0);
        float z = sigm_(iz0 + rA[1] + bZ0);
        float n = tanhf_(in0 + r * (rA[2] + bN0));
        float hy = n + z * (hv0 - n); hv0 = hy;
        pk[bb * 16 + u] = __builtin_bit_cast(unsigned short, (f16)hy);
        if (t == T_N - 1) hT[(size_t)gbi * H_N + unit] = hy;
      }
      // throttle: ensure layer-1 passed step t-7 before overwriting slot t&7
      POLL4(vT, kT, sT, eT)
      __syncthreads();   // pk ready + whole block passed throttle

      if (tid < 32) {    // tagged h0_t -> slot S8(t)
        ull v = ((const ull*)pk)[tid];
        v = (v & ~M) | (T8(t) ? M : 0ULL);
        ull* dp = (ull*)h0x + (size_t)S8(t) * 8192
                + (size_t)(8 * g + (tid >> 2)) * 128 + 4 * j + (tid & 3);
        __hip_atomic_store(dp, v, __ATOMIC_RELAXED, __HIP_MEMORY_SCOPE_AGENT);
      }
    }
  } else {
    // ---- layer 1: wih1 + whh1, 24 uint4 (spills tolerated: off-path) ----
    uint4 wq[24];
    {
      const uint4* wp = wbuf + ((size_t)j * 256 + tid) * 36;
#pragma unroll
      for (int i = 0; i < 24; ++i) wq[i] = wp[12 + i];
#pragma unroll
      for (int i = 0; i < 24; ++i)
        asm volatile("" : "+v"(wq[i].x), "+v"(wq[i].y), "+v"(wq[i].z), "+v"(wq[i].w));
    }
    float bR1 = 0, bZ1 = 0, bN1x = 0, bN1h = 0, hv1 = 0;
    if (wr) {
      bR1 = bih1[unit] + bhh1[unit];
      bZ1 = bih1[H_N + unit] + bhh1[H_N + unit];
      bN1x = bih1[2 * H_N + unit]; bN1h = bhh1[2 * H_N + unit];
      hv1 = hx[(size_t)(B_N + gbi) * H_N + unit];
    }

    for (int t = 0; t < T_N; ++t) {
      const ull* s1 = h1u + (size_t)S8(t - 1) * 8192 + (size_t)(8 * g) * 128;
      const ull e1 = T8(t - 1) ? M : 0ULL;
      const ull* s0 = h0u + (size_t)S8(t) * 8192 + (size_t)(8 * g) * 128;
      const ull e0 = T8(t) ? M : 0ULL;
      ull v1[4], v0[4];
      bool k1[4] = {false, false, false, false};
      bool k0[4] = {false, false, false, false};
#pragma unroll
      for (int e = 0; e < 4; ++e) {
        v1[e] = __hip_atomic_load(s1 + e * 256 + tid, __ATOMIC_RELAXED, __HIP_MEMORY_SCOPE_AGENT);
        v0[e] = __hip_atomic_load(s0 + e * 256 + tid, __ATOMIC_RELAXED, __HIP_MEMORY_SCOPE_AGENT);
      }
      POLL4(v1, k1, s1, e1)
#pragma unroll
      for (int e = 0; e < 4; ++e) sh1q[e * 256 + tid] = v1[e];
      POLL4(v0, k0, s0, e0)
#pragma unroll
      for (int e = 0; e < 4; ++e) shq[e * 256 + tid] = v0[e];
      __syncthreads();

      // B compute: x = h0_t, h = h1_{t-1}
      float aB[4][8];
#pragma unroll
      for (int q = 0; q < 4; ++q)
#pragma unroll
        for (int b8 = 0; b8 < 8; ++b8) aB[q][b8] = 0.f;
      const uint4* xp = (const uint4*)shq;
      const uint4* hp = (const uint4*)sh1q;
#pragma unroll
      for (int b8 = 0; b8 < 8; ++b8) {
        uint4 xc[4], hc[4];
#pragma unroll
        for (int c = 0; c < 4; ++c) {
          xc[c] = xp[b8 * 64 + s + 16 * c];
          hc[c] = hp[b8 * 64 + s + 16 * c];
        }
        float a0 = aB[0][b8], a1 = aB[1][b8], a2 = aB[2][b8], a3 = aB[3][b8];
#pragma unroll
        for (int c = 0; c < 4; ++c) {
          D4Q(a0, wq[0 + c], xc[c]);  D4Q(a0, wq[12 + c], hc[c]);
          D4Q(a1, wq[4 + c], xc[c]);  D4Q(a1, wq[16 + c], hc[c]);
          D4Q(a2, wq[8 + c], xc[c]);
          D4Q(a3, wq[20 + c], hc[c]);
        }
        aB[0][b8] = a0; aB[1][b8] = a1; aB[2][b8] = a2; aB[3][b8] = a3;
      }
      float rB[4];
      rscat8<4>(aB, rB, s);
      if (wr) {
        float r = sigm_(rB[0] + bR1);
        float z = sigm_(rB[1] + bZ1);
        float n = tanhf_(rB[2] + bN1x + r * (rB[3] + bN1h));
        float hy = n + z * (hv1 - n); hv1 = hy;
        pk[bb * 16 + u] = __builtin_bit_cast(unsigned short, (f16)hy);
      }
      __syncthreads();   // pk ready

      if (tid < 32) {    // tagged h1_t -> slot S8(t)
        ull v = ((const ull*)pk)[tid];
        v = (v & ~M) | (T8(t) ? M : 0ULL);
        ull* dp = (ull*)h1x + (size_t)S8(t) * 8192
                + (size_t)(8 * g + (tid >> 2)) * 128 + 4 * j + (tid & 3);
        __hip_atomic_store(dp, v, __ATOMIC_RELAXED, __HIP_MEMORY_SCOPE_AGENT);
      } else if (tid < 64) {  // fp32 out row t
        const int l = tid - 32;
        ull v = ((const ull*)pk)[l];
        f16x2 p0 = bch2((unsigned int)v), p1 = bch2((unsigned int)(v >> 32));
        float4 o = {(float)p0.x, (float)p0.y, (float)p1.x, (float)p1.y};
        float* op = out + ((size_t)t * B_N + 8 * g + (l >> 2)) * H_N + 16 * j + 4 * (l & 3);
        *(float4*)op = o;
        if (t == T_N - 1)
          *(float4*)(hT + (size_t)(B_N + 8 * g + (l >> 2)) * H_N + 16 * j + 4 * (l & 3)) = o;
      }
    }
  }
}

// ---------------------------------------------------------------------------
extern "C" void kernel_launch(void* const* d_in, const int* in_sizes, int n_in,
                              void* d_out, int out_size, void* d_ws, size_t ws_size,
                              hipStream_t stream)
{
  const float* x    = (const float*)d_in[0];
  const float* hx   = (const float*)d_in[1];
  const float* wih0 = (const float*)d_in[2];
  const float* whh0 = (const float*)d_in[3];
  const float* bih0 = (const float*)d_in[4];
  const float* bhh0 = (const float*)d_in[5];
  const float* wih1 = (const float*)d_in[6];
  const float* whh1 = (const float*)d_in[7];
  const float* bih1 = (const float*)d_in[8];
  const float* bhh1 = (const float*)d_in[9];
  float* out = (float*)d_out;            // [T*B*H] output, then [L*B*H] hT

  // workspace: gx | h0x 8*[B*H] f16 | h1x 8*[B*H] f16 | wbuf
  float* gxb = (float*)d_ws;
  f16*   h0x = (f16*)(gxb + (size_t)T_N * B_N * G3);
  f16*   h1x = h0x + 8 * B_N * H_N;
  uint4* wbuf = (uint4*)(h1x + 8 * B_N * H_N);   // 32*256*36 uint4 = 4.5 MB

  pack_h_init<<<128, 256, 0, stream>>>(hx, h0x, h1x);
  conv_w<<<(32 * 256 * 36) / 256, 256, 0, stream>>>(whh0, wih1, whh1, wbuf);

  dim3 gg(G3 / 64, (T_N * B_N) / 64);
  gemm_nt<<<gg, 256, 0, stream>>>(x, wih0, bih0, gxb, T_N * B_N, G3, I_N);

  gru_split<<<512, 256, 0, stream>>>(gxb, hx, wbuf,
                                     bih1, bhh0, bhh1,
                                     out, out + (size_t)T_N * B_N * H_N,
                                     h0x, h1x);
}

// Round 16
// 9488.833 us; speedup vs baseline: 1.1332x; 1.1332x over previous
//
#include <hip/hip_runtime.h>
#include <cstdint>
#include <cstddef>

#define T_N 1024
#define B_N 64
#define I_N 512
#define H_N 512
#define G3  (3*H_N)

typedef _Float16 f16;
typedef _Float16 f16x2 __attribute__((ext_vector_type(2)));
typedef unsigned long long ull;

// 8-deep exchange ring: generation d -> slot S8(d), LSB tag T8(d).
#define S8(d) (((d)+8)&7)
#define T8(d) ((((d)+8)>>3)&1)

__device__ __forceinline__ f16x2 mkh2(float a, float b) {
  f16x2 v; v.x = (_Float16)a; v.y = (_Float16)b; return v;
}
__device__ __forceinline__ f16x2 bch2(unsigned int u) {
  return __builtin_bit_cast(f16x2, u);
}
__device__ __forceinline__ float fdot2_(f16x2 a, f16x2 b, float c) {
#if __has_builtin(__builtin_amdgcn_fdot2)
  return __builtin_amdgcn_fdot2(a, b, c, false);
#else
  return fmaf((float)a.x, (float)b.x, fmaf((float)a.y, (float)b.y, c));
#endif
}
__device__ __forceinline__ float sigm_(float x) { return 1.f / (1.f + __expf(-x)); }
__device__ __forceinline__ float tanhf_(float x) {
  float xx = fminf(15.f, fmaxf(-15.f, x));
  float e = __expf(2.f * xx);
  return (e - 1.f) / (e + 1.f);
}

// ---------------------------------------------------------------------------
// GEMM: C[m][n] = sum_k A[m][k]*W[n][k] + bias[n]   (layer-0 input gates)
// ---------------------------------------------------------------------------
__global__ __launch_bounds__(256) void gemm_nt(
    const float* __restrict__ A,
    const float* __restrict__ W,
    const float* __restrict__ bias,
    float* __restrict__ C,
    int M, int N, int K)
{
  __shared__ float As[32][68];
  __shared__ float Ws[32][68];
  const int tid = threadIdx.x;
  const int n0 = blockIdx.x * 64;
  const int m0 = blockIdx.y * 64;
  const int ty = tid >> 4;
  const int tx = tid & 15;

  float acc[4][4];
#pragma unroll
  for (int i = 0; i < 4; ++i)
#pragma unroll
    for (int jj = 0; jj < 4; ++jj) acc[i][jj] = 0.f;

  for (int k0 = 0; k0 < K; k0 += 32) {
#pragma unroll
    for (int i = 0; i < 2; ++i) {
      int idx = tid + i * 256;
      int r   = idx >> 3;
      int c4  = idx & 7;
      float4 va = *(const float4*)(A + (size_t)(m0 + r) * K + k0 + c4 * 4);
      As[c4*4+0][r] = va.x; As[c4*4+1][r] = va.y;
      As[c4*4+2][r] = va.z; As[c4*4+3][r] = va.w;
      float4 vw = *(const float4*)(W + (size_t)(n0 + r) * K + k0 + c4 * 4);
      Ws[c4*4+0][r] = vw.x; Ws[c4*4+1][r] = vw.y;
      Ws[c4*4+2][r] = vw.z; Ws[c4*4+3][r] = vw.w;
    }
    __syncthreads();
#pragma unroll
    for (int k = 0; k < 32; ++k) {
      float4 a = *(const float4*)&As[k][ty * 4];
      float4 w = *(const float4*)&Ws[k][tx * 4];
      acc[0][0] += a.x*w.x; acc[0][1] += a.x*w.y; acc[0][2] += a.x*w.z; acc[0][3] += a.x*w.w;
      acc[1][0] += a.y*w.x; acc[1][1] += a.y*w.y; acc[1][2] += a.y*w.z; acc[1][3] += a.y*w.w;
      acc[2][0] += a.z*w.x; acc[2][1] += a.z*w.y; acc[2][2] += a.z*w.z; acc[2][3] += a.z*w.w;
      acc[3][0] += a.w*w.x; acc[3][1] += a.w*w.y; acc[3][2] += a.w*w.z; acc[3][3] += a.w*w.w;
    }
    __syncthreads();
  }

  float4 bv = *(const float4*)(bias + n0 + tx * 4);
#pragma unroll
  for (int i = 0; i < 4; ++i) {
    int row = m0 + ty * 4 + i;
    float4 o;
    o.x = acc[i][0] + bv.x; o.y = acc[i][1] + bv.y;
    o.z = acc[i][2] + bv.z; o.w = acc[i][3] + bv.w;
    *(float4*)(C + (size_t)row * N + n0 + tx * 4) = o;
  }
}

// init: pack fp32 hx -> f16 ring slot S8(-1)=7 with tag T8(-1)=0 (LSB clear)
__global__ __launch_bounds__(256) void pack_h_init(
    const float* __restrict__ hx, f16* __restrict__ h0x, f16* __restrict__ h1x)
{
  int i = blockIdx.x * 256 + threadIdx.x;   // 0..32767
  unsigned short a = __builtin_bit_cast(unsigned short, (f16)hx[i]) & 0xFFFEu;
  unsigned short b = __builtin_bit_cast(unsigned short, (f16)hx[B_N * H_N + i]) & 0xFFFEu;
  ((unsigned short*)h0x)[7 * B_N * H_N + i] = a;
  ((unsigned short*)h1x)[7 * B_N * H_N + i] = b;
}

// ---------------------------------------------------------------------------
// conv_w: f16 weights, per-(j,tid512) layout: wbuf[(j*512+tid)*18 + idx],
// idx = mat*6 + q*2 + c (mat 0=whh0, 1=wih1, 2=whh1; q=gate; c=0,1);
// uint4 = 8 halfs at k = 8*s + 256*c for thread (u=tid>>5, s=tid&31).
// ---------------------------------------------------------------------------
__global__ __launch_bounds__(256) void conv_w(
    const float* __restrict__ whh0, const float* __restrict__ wih1,
    const float* __restrict__ whh1, uint4* __restrict__ wbuf)
{
  int gid = blockIdx.x * 256 + threadIdx.x;        // 0..294911
  int idx = gid % 18, rem = gid / 18;
  int tid = rem % 512, j = rem / 512;
  int u = tid >> 5, s = tid & 31;
  int mat = idx / 6, q = (idx % 6) / 2, c = idx % 2;
  const float* src = mat == 0 ? whh0 : (mat == 1 ? wih1 : whh1);
  const float* p = src + (size_t)(q * H_N + 16 * j + u) * H_N + 8 * s + 256 * c;
  uint4 o;
  o.x = __builtin_bit_cast(unsigned int, mkh2(p[0], p[1]));
  o.y = __builtin_bit_cast(unsigned int, mkh2(p[2], p[3]));
  o.z = __builtin_bit_cast(unsigned int, mkh2(p[4], p[5]));
  o.w = __builtin_bit_cast(unsigned int, mkh2(p[6], p[7]));
  wbuf[gid] = o;
}

#define D4Q(acc, wv, vv)                               \
  acc = fdot2_(bch2((wv).x), bch2((vv).x), acc);       \
  acc = fdot2_(bch2((wv).y), bch2((vv).y), acc);       \
  acc = fdot2_(bch2((wv).z), bch2((vv).z), acc);       \
  acc = fdot2_(bch2((wv).w), bch2((vv).w), acc);

// reduce-scatter 8 accumulators over the 32-lane s-group (5 shuffle levels).
// After: every lane holds the full sum for bb = 4(s&1)+2((s>>1)&1)+((s>>2)&1).
template <int NQ>
__device__ __forceinline__ void rscat8w(float a[][8], float* r, int s) {
#pragma unroll
  for (int q = 0; q < NQ; ++q) {
    float k4[4];
#pragma unroll
    for (int i = 0; i < 4; ++i) {
      float snd = (s & 1) ? a[q][i] : a[q][4 + i];
      float kp  = (s & 1) ? a[q][4 + i] : a[q][i];
      k4[i] = kp + __shfl_xor(snd, 1);
    }
    float k2[2];
#pragma unroll
    for (int i = 0; i < 2; ++i) {
      float snd = (s & 2) ? k4[i] : k4[2 + i];
      float kp  = (s & 2) ? k4[2 + i] : k4[i];
      k2[i] = kp + __shfl_xor(snd, 2);
    }
    float snd = (s & 4) ? k2[0] : k2[1];
    float kp  = (s & 4) ? k2[1] : k2[0];
    float k1 = kp + __shfl_xor(snd, 4);
    k1 = k1 + __shfl_xor(k1, 8);
    r[q] = k1 + __shfl_xor(k1, 16);
  }
}

#define POLL2(vv, kk, sp, ee)                                                  \
  for (;;) {                                                                   \
    bool all_ = true;                                                          \
    _Pragma("unroll")                                                          \
    for (int e_ = 0; e_ < 2; ++e_) {                                           \
      if (!kk[e_]) kk[e_] = ((vv[e_] & M) == ee);                              \
      all_ = all_ && kk[e_];                                                   \
    }                                                                          \
    if (__all(all_)) break;                                                    \
    __builtin_amdgcn_s_sleep(1);                                               \
    _Pragma("unroll")                                                          \
    for (int e_ = 0; e_ < 2; ++e_)                                             \
      if (!kk[e_]) vv[e_] = __hip_atomic_load(sp + e_ * 512 + tid,             \
                     __ATOMIC_RELAXED, __HIP_MEMORY_SCOPE_AGENT);              \
  }

// ---------------------------------------------------------------------------
// Decoupled-layer persistent scan, 512 threads/block so NOTHING spills:
// L0 blocks (bid<256) hold 6 weight uint4 (24 VGPRs), L1 blocks hold 12
// (48 VGPRs) -- both inside the RA's ~130 budget (round-15 lesson: 24 uint4
// = 96 VGPRs forced L1 into full scratch-spill, and the throttle made L0
// inherit that pace). Lane-consecutive LDS reads (s+32c), lanes 32-63
// broadcast -- no round-14 bank conflicts. Ring protocol as round 15.
// ---------------------------------------------------------------------------
__global__ __launch_bounds__(512) void gru_split(
    const float* __restrict__ gx,    // [T][64][1536] layer-0 input gates
    const float* __restrict__ hx,    // [2][64][512] fp32 initial h
    const uint4* __restrict__ wbuf,  // pre-converted f16 weights
    const float* __restrict__ bih1, const float* __restrict__ bhh0,
    const float* __restrict__ bhh1,
    float* __restrict__ out,         // [T][64][512]
    float* __restrict__ hT,          // [2][64][512]
    f16* __restrict__ h0x, f16* __restrict__ h1x)  // 8-slot tagged rings
{
  __shared__ __align__(16) ull shq[1024];       // 8 KB staged h0
  __shared__ __align__(16) ull sh1q[1024];      // 8 KB staged h1 (L1 only)
  __shared__ __align__(8) unsigned short pk[128];

  const int tid = threadIdx.x;   // 0..511
  const bool L0 = (blockIdx.x < 256);
  const int lb = L0 ? blockIdx.x : blockIdx.x - 256;
  const int g = lb & 7;          // batch group (8 batches)
  const int j = lb >> 3;         // units 16j..16j+15
  const int u = tid >> 5;        // unit 0..15
  const int s = tid & 31;        // k-split 0..31
  const ull M = 0x0001000100010001ULL;

  const int bb   = 4 * (s & 1) + 2 * ((s >> 1) & 1) + ((s >> 2) & 1);
  const int unit = 16 * j + u;
  const int gbi  = 8 * g + bb;
  const bool wr  = (s < 8);
  const ull* h0u = (const ull*)h0x;
  const ull* h1u = (const ull*)h1x;

  if (L0) {
    // ---- layer 0: whh0 slice, 6 uint4 (24 VGPRs) ----
    uint4 wq[6];
    {
      const uint4* wp = wbuf + ((size_t)j * 512 + tid) * 18;
#pragma unroll
      for (int i = 0; i < 6; ++i) wq[i] = wp[i];
#pragma unroll
      for (int i = 0; i < 6; ++i)
        asm volatile("" : "+v"(wq[i].x), "+v"(wq[i].y), "+v"(wq[i].z), "+v"(wq[i].w));
    }
    float bR0 = 0, bZ0 = 0, bN0 = 0, hv0 = 0;
    if (wr) {
      bR0 = bhh0[unit]; bZ0 = bhh0[H_N + unit]; bN0 = bhh0[2 * H_N + unit];
      hv0 = hx[(size_t)gbi * H_N + unit];
    }

    for (int t = 0; t < T_N; ++t) {
      const ull* s0 = h0u + (size_t)S8(t - 1) * 8192 + (size_t)(8 * g) * 128;
      const ull e0 = T8(t - 1) ? M : 0ULL;
      ull v0[2]; bool k0[2] = {false, false};
#pragma unroll
      for (int e = 0; e < 2; ++e)
        v0[e] = __hip_atomic_load(s0 + e * 512 + tid, __ATOMIC_RELAXED, __HIP_MEMORY_SCOPE_AGENT);
      const bool thr = (t >= 7);
      const ull* sT = h1u + (size_t)S8(t - 7) * 8192 + (size_t)(8 * g) * 128;
      const ull eT = T8(t - 7) ? M : 0ULL;
      ull vT[2]; bool kT[2] = {!thr, !thr};
      if (thr) {
#pragma unroll
        for (int e = 0; e < 2; ++e)
          vT[e] = __hip_atomic_load(sT + e * 512 + tid, __ATOMIC_RELAXED, __HIP_MEMORY_SCOPE_AGENT);
      }
      float ir0 = 0, iz0 = 0, in0 = 0;
      if (wr) {
        const float* p = gx + ((size_t)t * B_N + gbi) * G3 + unit;
        ir0 = p[0]; iz0 = p[H_N]; in0 = p[2 * H_N];
      }

      POLL2(v0, k0, s0, e0)
#pragma unroll
      for (int e = 0; e < 2; ++e) shq[e * 512 + tid] = v0[e];
      __syncthreads();

      // A compute: 3 gates x 8 batches, 192 dot2/thread
      float aA[3][8];
#pragma unroll
      for (int q = 0; q < 3; ++q)
#pragma unroll
        for (int b8 = 0; b8 < 8; ++b8) aA[q][b8] = 0.f;
      const uint4* xp = (const uint4*)shq;
#pragma unroll
      for (int b8 = 0; b8 < 8; ++b8) {
        uint4 xc[2];
        xc[0] = xp[b8 * 64 + s];
        xc[1] = xp[b8 * 64 + s + 32];
        float a0 = aA[0][b8], a1 = aA[1][b8], a2 = aA[2][b8];
#pragma unroll
        for (int c = 0; c < 2; ++c) {
          D4Q(a0, wq[0 + c], xc[c]);
          D4Q(a1, wq[2 + c], xc[c]);
          D4Q(a2, wq[4 + c], xc[c]);
        }
        aA[0][b8] = a0; aA[1][b8] = a1; aA[2][b8] = a2;
      }
      float rA[3];
      rscat8w<3>(aA, rA, s);
      if (wr) {
        float r = sigm_(ir0 + rA[0] + bR0);
        float z = sigm_(iz0 + rA[1] + bZ0);
        float n = tanhf_(in0 + r * (rA[2] + bN0));
        float hy = n + z * (hv0 - n); hv0 = hy;
        pk[bb * 16 + u] = __builtin_bit_cast(unsigned short, (f16)hy);
        if (t == T_N - 1) hT[(size_t)gbi * H_N + unit] = hy;
      }
      POLL2(vT, kT, sT, eT)   // throttle: layer-1 must pass t-7
      __syncthreads();

      if (tid < 32) {    // tagged h0_t -> slot S8(t)
        ull v = ((const ull*)pk)[tid];
        v = (v & ~M) | (T8(t) ? M : 0ULL);
        ull* dp = (ull*)h0x + (size_t)S8(t) * 8192
                + (size_t)(8 * g + (tid >> 2)) * 128 + 4 * j + (tid & 3);
        __hip_atomic_store(dp, v, __ATOMIC_RELAXED, __HIP_MEMORY_SCOPE_AGENT);
      }
    }
  } else {
    // ---- layer 1: wih1 + whh1, 12 uint4 (48 VGPRs) ----
    uint4 wq[12];
    {
      const uint4* wp = wbuf + ((size_t)j * 512 + tid) * 18;
#pragma unroll
      for (int i = 0; i < 12; ++i) wq[i] = wp[6 + i];
#pragma unroll
      for (int i = 0; i < 12; ++i)
        asm volatile("" : "+v"(wq[i].x), "+v"(wq[i].y), "+v"(wq[i].z), "+v"(wq[i].w));
    }
    float bR1 = 0, bZ1 = 0, bN1x = 0, bN1h = 0, hv1 = 0;
    if (wr) {
      bR1 = bih1[unit] + bhh1[unit];
      bZ1 = bih1[H_N + unit] + bhh1[H_N + unit];
      bN1x = bih1[2 * H_N + unit]; bN1h = bhh1[2 * H_N + unit];
      hv1 = hx[(size_t)(B_N + gbi) * H_N + unit];
    }

    for (int t = 0; t < T_N; ++t) {
      const ull* s1 = h1u + (size_t)S8(t - 1) * 8192 + (size_t)(8 * g) * 128;
      const ull e1 = T8(t - 1) ? M : 0ULL;
      const ull* s0 = h0u + (size_t)S8(t) * 8192 + (size_t)(8 * g) * 128;
      const ull e0 = T8(t) ? M : 0ULL;
      ull v1[2], v0[2];
      bool k1[2] = {false, false};
      bool k0[2] = {false, false};
#pragma unroll
      for (int e = 0; e < 2; ++e) {
        v1[e] = __hip_atomic_load(s1 + e * 512 + tid, __ATOMIC_RELAXED, __HIP_MEMORY_SCOPE_AGENT);
        v0[e] = __hip_atomic_load(s0 + e * 512 + tid, __ATOMIC_RELAXED, __HIP_MEMORY_SCOPE_AGENT);
      }
      POLL2(v1, k1, s1, e1)
#pragma unroll
      for (int e = 0; e < 2; ++e) sh1q[e * 512 + tid] = v1[e];
      POLL2(v0, k0, s0, e0)
#pragma unroll
      for (int e = 0; e < 2; ++e) shq[e * 512 + tid] = v0[e];
      __syncthreads();

      // B compute: x = h0_t, h = h1_{t-1}; 384 dot2/thread
      float aB[4][8];
#pragma unroll
      for (int q = 0; q < 4; ++q)
#pragma unroll
        for (int b8 = 0; b8 < 8; ++b8) aB[q][b8] = 0.f;
      const uint4* xp = (const uint4*)shq;
      const uint4* hp = (const uint4*)sh1q;
#pragma unroll
      for (int b8 = 0; b8 < 8; ++b8) {
        uint4 xc[2], hc[2];
        xc[0] = xp[b8 * 64 + s];      xc[1] = xp[b8 * 64 + s + 32];
        hc[0] = hp[b8 * 64 + s];      hc[1] = hp[b8 * 64 + s + 32];
        float a0 = aB[0][b8], a1 = aB[1][b8], a2 = aB[2][b8], a3 = aB[3][b8];
#pragma unroll
        for (int c = 0; c < 2; ++c) {
          D4Q(a0, wq[0 + c], xc[c]);  D4Q(a0, wq[6 + c],  hc[c]);
          D4Q(a1, wq[2 + c], xc[c]);  D4Q(a1, wq[8 + c],  hc[c]);
          D4Q(a2, wq[4 + c], xc[c]);
          D4Q(a3, wq[10 + c], hc[c]);
        }
        aB[0][b8] = a0; aB[1][b8] = a1; aB[2][b8] = a2; aB[3][b8] = a3;
      }
      float rB[4];
      rscat8w<4>(aB, rB, s);
      if (wr) {
        float r = sigm_(rB[0] + bR1);
        float z = sigm_(rB[1] + bZ1);
        float n = tanhf_(rB[2] + bN1x + r * (rB[3] + bN1h));
        float hy = n + z * (hv1 - n); hv1 = hy;
        pk[bb * 16 + u] = __builtin_bit_cast(unsigned short, (f16)hy);
      }
      __syncthreads();

      if (tid < 32) {    // tagged h1_t -> slot S8(t)
        ull v = ((const ull*)pk)[tid];
        v = (v & ~M) | (T8(t) ? M : 0ULL);
        ull* dp = (ull*)h1x + (size_t)S8(t) * 8192
                + (size_t)(8 * g + (tid >> 2)) * 128 + 4 * j + (tid & 3);
        __hip_atomic_store(dp, v, __ATOMIC_RELAXED, __HIP_MEMORY_SCOPE_AGENT);
      } else if (tid < 64) {  // fp32 out row t
        const int l = tid - 32;
        ull v = ((const ull*)pk)[l];
        f16x2 p0 = bch2((unsigned int)v), p1 = bch2((unsigned int)(v >> 32));
        float4 o = {(float)p0.x, (float)p0.y, (float)p1.x, (float)p1.y};
        float* op = out + ((size_t)t * B_N + 8 * g + (l >> 2)) * H_N + 16 * j + 4 * (l & 3);
        *(float4*)op = o;
        if (t == T_N - 1)
          *(float4*)(hT + (size_t)(B_N + 8 * g + (l >> 2)) * H_N + 16 * j + 4 * (l & 3)) = o;
      }
    }
  }
}

// ---------------------------------------------------------------------------
extern "C" void kernel_launch(void* const* d_in, const int* in_sizes, int n_in,
                              void* d_out, int out_size, void* d_ws, size_t ws_size,
                              hipStream_t stream)
{
  const float* x    = (const float*)d_in[0];
  const float* hx   = (const float*)d_in[1];
  const float* wih0 = (const float*)d_in[2];
  const float* whh0 = (const float*)d_in[3];
  const float* bih0 = (const float*)d_in[4];
  const float* bhh0 = (const float*)d_in[5];
  const float* wih1 = (const float*)d_in[6];
  const float* whh1 = (const float*)d_in[7];
  const float* bih1 = (const float*)d_in[8];
  const float* bhh1 = (const float*)d_in[9];
  float* out = (float*)d_out;            // [T*B*H] output, then [L*B*H] hT

  // workspace: gx | h0x 8*[B*H] f16 | h1x 8*[B*H] f16 | wbuf
  float* gxb = (float*)d_ws;
  f16*   h0x = (f16*)(gxb + (size_t)T_N * B_N * G3);
  f16*   h1x = h0x + 8 * B_N * H_N;
  uint4* wbuf = (uint4*)(h1x + 8 * B_N * H_N);   // 32*512*18 uint4 = 4.5 MB

  pack_h_init<<<128, 256, 0, stream>>>(hx, h0x, h1x);
  conv_w<<<(32 * 512 * 18) / 256, 256, 0, stream>>>(whh0, wih1, whh1, wbuf);

  dim3 gg(G3 / 64, (T_N * B_N) / 64);
  gemm_nt<<<gg, 256, 0, stream>>>(x, wih0, bih0, gxb, T_N * B_N, G3, I_N);

  gru_split<<<512, 512, 0, stream>>>(gxb, hx, wbuf,
                                     bih1, bhh0, bhh1,
                                     out, out + (size_t)T_N * B_N * H_N,
                                     h0x, h1x);
}

// Round 17
// 9032.562 us; speedup vs baseline: 1.1904x; 1.0505x over previous
//
#include <hip/hip_runtime.h>
#include <cstdint>
#include <cstddef>

#define T_N 1024
#define B_N 64
#define I_N 512
#define H_N 512
#define G3  (3*H_N)

typedef _Float16 f16;
typedef _Float16 f16x2 __attribute__((ext_vector_type(2)));
typedef unsigned long long ull;

// 8-deep exchange ring: generation d -> slot S8(d), LSB tag T8(d).
#define S8(d) (((d)+8)&7)
#define T8(d) ((((d)+8)>>3)&1)

__device__ __forceinline__ f16x2 mkh2(float a, float b) {
  f16x2 v; v.x = (_Float16)a; v.y = (_Float16)b; return v;
}
__device__ __forceinline__ f16x2 bch2(unsigned int u) {
  return __builtin_bit_cast(f16x2, u);
}
__device__ __forceinline__ float fdot2_(f16x2 a, f16x2 b, float c) {
#if __has_builtin(__builtin_amdgcn_fdot2)
  return __builtin_amdgcn_fdot2(a, b, c, false);
#else
  return fmaf((float)a.x, (float)b.x, fmaf((float)a.y, (float)b.y, c));
#endif
}
__device__ __forceinline__ float sigm_(float x) { return 1.f / (1.f + __expf(-x)); }
__device__ __forceinline__ float tanhf_(float x) {
  float xx = fminf(15.f, fmaxf(-15.f, x));
  float e = __expf(2.f * xx);
  return (e - 1.f) / (e + 1.f);
}

// ---------------------------------------------------------------------------
// GEMM: C[m][n] = sum_k A[m][k]*W[n][k] + bias[n]   (layer-0 input gates)
// ---------------------------------------------------------------------------
__global__ __launch_bounds__(256) void gemm_nt(
    const float* __restrict__ A,
    const float* __restrict__ W,
    const float* __restrict__ bias,
    float* __restrict__ C,
    int M, int N, int K)
{
  __shared__ float As[32][68];
  __shared__ float Ws[32][68];
  const int tid = threadIdx.x;
  const int n0 = blockIdx.x * 64;
  const int m0 = blockIdx.y * 64;
  const int ty = tid >> 4;
  const int tx = tid & 15;

  float acc[4][4];
#pragma unroll
  for (int i = 0; i < 4; ++i)
#pragma unroll
    for (int jj = 0; jj < 4; ++jj) acc[i][jj] = 0.f;

  for (int k0 = 0; k0 < K; k0 += 32) {
#pragma unroll
    for (int i = 0; i < 2; ++i) {
      int idx = tid + i * 256;
      int r   = idx >> 3;
      int c4  = idx & 7;
      float4 va = *(const float4*)(A + (size_t)(m0 + r) * K + k0 + c4 * 4);
      As[c4*4+0][r] = va.x; As[c4*4+1][r] = va.y;
      As[c4*4+2][r] = va.z; As[c4*4+3][r] = va.w;
      float4 vw = *(const float4*)(W + (size_t)(n0 + r) * K + k0 + c4 * 4);
      Ws[c4*4+0][r] = vw.x; Ws[c4*4+1][r] = vw.y;
      Ws[c4*4+2][r] = vw.z; Ws[c4*4+3][r] = vw.w;
    }
    __syncthreads();
#pragma unroll
    for (int k = 0; k < 32; ++k) {
      float4 a = *(const float4*)&As[k][ty * 4];
      float4 w = *(const float4*)&Ws[k][tx * 4];
      acc[0][0] += a.x*w.x; acc[0][1] += a.x*w.y; acc[0][2] += a.x*w.z; acc[0][3] += a.x*w.w;
      acc[1][0] += a.y*w.x; acc[1][1] += a.y*w.y; acc[1][2] += a.y*w.z; acc[1][3] += a.y*w.w;
      acc[2][0] += a.z*w.x; acc[2][1] += a.z*w.y; acc[2][2] += a.z*w.z; acc[2][3] += a.z*w.w;
      acc[3][0] += a.w*w.x; acc[3][1] += a.w*w.y; acc[3][2] += a.w*w.z; acc[3][3] += a.w*w.w;
    }
    __syncthreads();
  }

  float4 bv = *(const float4*)(bias + n0 + tx * 4);
#pragma unroll
  for (int i = 0; i < 4; ++i) {
    int row = m0 + ty * 4 + i;
    float4 o;
    o.x = acc[i][0] + bv.x; o.y = acc[i][1] + bv.y;
    o.z = acc[i][2] + bv.z; o.w = acc[i][3] + bv.w;
    *(float4*)(C + (size_t)row * N + n0 + tx * 4) = o;
  }
}

// init: pack fp32 hx -> f16 ring slot S8(-1)=7 with tag T8(-1)=0 (LSB clear)
__global__ __launch_bounds__(256) void pack_h_init(
    const float* __restrict__ hx, f16* __restrict__ h0x, f16* __restrict__ h1x)
{
  int i = blockIdx.x * 256 + threadIdx.x;   // 0..32767
  unsigned short a = __builtin_bit_cast(unsigned short, (f16)hx[i]) & 0xFFFEu;
  unsigned short b = __builtin_bit_cast(unsigned short, (f16)hx[B_N * H_N + i]) & 0xFFFEu;
  ((unsigned short*)h0x)[7 * B_N * H_N + i] = a;
  ((unsigned short*)h1x)[7 * B_N * H_N + i] = b;
}

// ---------------------------------------------------------------------------
// conv_w: f16 weights, per-(j,tid512) layout: wbuf[(j*512+tid)*18 + idx],
// idx = mat*6 + q*2 + c (mat 0=whh0, 1=wih1, 2=whh1; q=gate; c=0,1);
// uint4 = 8 halfs at k = 8*s + 256*c for thread (u=tid>>5, s=tid&31).
// ---------------------------------------------------------------------------
__global__ __launch_bounds__(256) void conv_w(
    const float* __restrict__ whh0, const float* __restrict__ wih1,
    const float* __restrict__ whh1, uint4* __restrict__ wbuf)
{
  int gid = blockIdx.x * 256 + threadIdx.x;        // 0..294911
  int idx = gid % 18, rem = gid / 18;
  int tid = rem % 512, j = rem / 512;
  int u = tid >> 5, s = tid & 31;
  int mat = idx / 6, q = (idx % 6) / 2, c = idx % 2;
  const float* src = mat == 0 ? whh0 : (mat == 1 ? wih1 : whh1);
  const float* p = src + (size_t)(q * H_N + 16 * j + u) * H_N + 8 * s + 256 * c;
  uint4 o;
  o.x = __builtin_bit_cast(unsigned int, mkh2(p[0], p[1]));
  o.y = __builtin_bit_cast(unsigned int, mkh2(p[2], p[3]));
  o.z = __builtin_bit_cast(unsigned int, mkh2(p[4], p[5]));
  o.w = __builtin_bit_cast(unsigned int, mkh2(p[6], p[7]));
  wbuf[gid] = o;
}

#define D4Q(acc, wv, vv)                               \
  acc = fdot2_(bch2((wv).x), bch2((vv).x), acc);       \
  acc = fdot2_(bch2((wv).y), bch2((vv).y), acc);       \
  acc = fdot2_(bch2((wv).z), bch2((vv).z), acc);       \
  acc = fdot2_(bch2((wv).w), bch2((vv).w), acc);

// reduce-scatter 8 accumulators over the 32-lane s-group (5 shuffle levels).
// After: every lane holds the full sum for bb = 4(s&1)+2((s>>1)&1)+((s>>2)&1).
template <int NQ>
__device__ __forceinline__ void rscat8w(float a[][8], float* r, int s) {
#pragma unroll
  for (int q = 0; q < NQ; ++q) {
    float k4[4];
#pragma unroll
    for (int i = 0; i < 4; ++i) {
      float snd = (s & 1) ? a[q][i] : a[q][4 + i];
      float kp  = (s & 1) ? a[q][4 + i] : a[q][i];
      k4[i] = kp + __shfl_xor(snd, 1);
    }
    float k2[2];
#pragma unroll
    for (int i = 0; i < 2; ++i) {
      float snd = (s & 2) ? k4[i] : k4[2 + i];
      float kp  = (s & 2) ? k4[2 + i] : k4[i];
      k2[i] = kp + __shfl_xor(snd, 2);
    }
    float snd = (s & 4) ? k2[0] : k2[1];
    float kp  = (s & 4) ? k2[1] : k2[0];
    float k1 = kp + __shfl_xor(snd, 4);
    k1 = k1 + __shfl_xor(k1, 8);
    r[q] = k1 + __shfl_xor(k1, 16);
  }
}

#define POLL2(vv, kk, sp, ee)                                                  \
  for (;;) {                                                                   \
    bool all_ = true;                                                          \
    _Pragma("unroll")                                                          \
    for (int e_ = 0; e_ < 2; ++e_) {                                           \
      if (!kk[e_]) kk[e_] = ((vv[e_] & M) == ee);                              \
      all_ = all_ && kk[e_];                                                   \
    }                                                                          \
    if (__all(all_)) break;                                                    \
    __builtin_amdgcn_s_sleep(1);                                               \
    _Pragma("unroll")                                                          \
    for (int e_ = 0; e_ < 2; ++e_)                                             \
      if (!kk[e_]) vv[e_] = __hip_atomic_load(sp + e_ * 512 + tid,             \
                     __ATOMIC_RELAXED, __HIP_MEMORY_SCOPE_AGENT);              \
  }

// ---------------------------------------------------------------------------
// Decoupled-layer persistent scan. ROUND-17 CHANGE (the only one):
// __launch_bounds__(512, 4) -- min 4 waves/EU sets the RA's VGPR budget to
// 512/4 = 128 (round 16's plain (512) defaulted to 64 -> everything spilled).
// L0 needs ~88 live regs, L1 ~126: both fit -> spill-free AND 4 waves/SIMD
// (2 mixed blocks/CU) for latency hiding. First clean run of that cell.
// ---------------------------------------------------------------------------
__global__ __launch_bounds__(512, 4) void gru_split(
    const float* __restrict__ gx,    // [T][64][1536] layer-0 input gates
    const float* __restrict__ hx,    // [2][64][512] fp32 initial h
    const uint4* __restrict__ wbuf,  // pre-converted f16 weights
    const float* __restrict__ bih1, const float* __restrict__ bhh0,
    const float* __restrict__ bhh1,
    float* __restrict__ out,         // [T][64][512]
    float* __restrict__ hT,          // [2][64][512]
    f16* __restrict__ h0x, f16* __restrict__ h1x)  // 8-slot tagged rings
{
  __shared__ __align__(16) ull shq[1024];       // 8 KB staged h0
  __shared__ __align__(16) ull sh1q[1024];      // 8 KB staged h1 (L1 only)
  __shared__ __align__(8) unsigned short pk[128];

  const int tid = threadIdx.x;   // 0..511
  const bool L0 = (blockIdx.x < 256);
  const int lb = L0 ? blockIdx.x : blockIdx.x - 256;
  const int g = lb & 7;          // batch group (8 batches)
  const int j = lb >> 3;         // units 16j..16j+15
  const int u = tid >> 5;        // unit 0..15
  const int s = tid & 31;        // k-split 0..31
  const ull M = 0x0001000100010001ULL;

  const int bb   = 4 * (s & 1) + 2 * ((s >> 1) & 1) + ((s >> 2) & 1);
  const int unit = 16 * j + u;
  const int gbi  = 8 * g + bb;
  const bool wr  = (s < 8);
  const ull* h0u = (const ull*)h0x;
  const ull* h1u = (const ull*)h1x;

  if (L0) {
    // ---- layer 0: whh0 slice, 6 uint4 (24 VGPRs) ----
    uint4 wq[6];
    {
      const uint4* wp = wbuf + ((size_t)j * 512 + tid) * 18;
#pragma unroll
      for (int i = 0; i < 6; ++i) wq[i] = wp[i];
#pragma unroll
      for (int i = 0; i < 6; ++i)
        asm volatile("" : "+v"(wq[i].x), "+v"(wq[i].y), "+v"(wq[i].z), "+v"(wq[i].w));
    }
    float bR0 = 0, bZ0 = 0, bN0 = 0, hv0 = 0;
    if (wr) {
      bR0 = bhh0[unit]; bZ0 = bhh0[H_N + unit]; bN0 = bhh0[2 * H_N + unit];
      hv0 = hx[(size_t)gbi * H_N + unit];
    }

    for (int t = 0; t < T_N; ++t) {
      const ull* s0 = h0u + (size_t)S8(t - 1) * 8192 + (size_t)(8 * g) * 128;
      const ull e0 = T8(t - 1) ? M : 0ULL;
      ull v0[2]; bool k0[2] = {false, false};
#pragma unroll
      for (int e = 0; e < 2; ++e)
        v0[e] = __hip_atomic_load(s0 + e * 512 + tid, __ATOMIC_RELAXED, __HIP_MEMORY_SCOPE_AGENT);
      const bool thr = (t >= 7);
      const ull* sT = h1u + (size_t)S8(t - 7) * 8192 + (size_t)(8 * g) * 128;
      const ull eT = T8(t - 7) ? M : 0ULL;
      ull vT[2]; bool kT[2] = {!thr, !thr};
      if (thr) {
#pragma unroll
        for (int e = 0; e < 2; ++e)
          vT[e] = __hip_atomic_load(sT + e * 512 + tid, __ATOMIC_RELAXED, __HIP_MEMORY_SCOPE_AGENT);
      }
      float ir0 = 0, iz0 = 0, in0 = 0;
      if (wr) {
        const float* p = gx + ((size_t)t * B_N + gbi) * G3 + unit;
        ir0 = p[0]; iz0 = p[H_N]; in0 = p[2 * H_N];
      }

      POLL2(v0, k0, s0, e0)
#pragma unroll
      for (int e = 0; e < 2; ++e) shq[e * 512 + tid] = v0[e];
      __syncthreads();

      // A compute: 3 gates x 8 batches, 192 dot2/thread
      float aA[3][8];
#pragma unroll
      for (int q = 0; q < 3; ++q)
#pragma unroll
        for (int b8 = 0; b8 < 8; ++b8) aA[q][b8] = 0.f;
      const uint4* xp = (const uint4*)shq;
#pragma unroll
      for (int b8 = 0; b8 < 8; ++b8) {
        uint4 xc[2];
        xc[0] = xp[b8 * 64 + s];
        xc[1] = xp[b8 * 64 + s + 32];
        float a0 = aA[0][b8], a1 = aA[1][b8], a2 = aA[2][b8];
#pragma unroll
        for (int c = 0; c < 2; ++c) {
          D4Q(a0, wq[0 + c], xc[c]);
          D4Q(a1, wq[2 + c], xc[c]);
          D4Q(a2, wq[4 + c], xc[c]);
        }
        aA[0][b8] = a0; aA[1][b8] = a1; aA[2][b8] = a2;
      }
      float rA[3];
      rscat8w<3>(aA, rA, s);
      if (wr) {
        float r = sigm_(ir0 + rA[0] + bR0);
        float z = sigm_(iz0 + rA[1] + bZ0);
        float n = tanhf_(in0 + r * (rA[2] + bN0));
        float hy = n + z * (hv0 - n); hv0 = hy;
        pk[bb * 16 + u] = __builtin_bit_cast(unsigned short, (f16)hy);
        if (t == T_N - 1) hT[(size_t)gbi * H_N + unit] = hy;
      }
      POLL2(vT, kT, sT, eT)   // throttle: layer-1 must pass t-7
      __syncthreads();

      if (tid < 32) {    // tagged h0_t -> slot S8(t)
        ull v = ((const ull*)pk)[tid];
        v = (v & ~M) | (T8(t) ? M : 0ULL);
        ull* dp = (ull*)h0x + (size_t)S8(t) * 8192
                + (size_t)(8 * g + (tid >> 2)) * 128 + 4 * j + (tid & 3);
        __hip_atomic_store(dp, v, __ATOMIC_RELAXED, __HIP_MEMORY_SCOPE_AGENT);
      }
    }
  } else {
    // ---- layer 1: wih1 + whh1, 12 uint4 (48 VGPRs) ----
    uint4 wq[12];
    {
      const uint4* wp = wbuf + ((size_t)j * 512 + tid) * 18;
#pragma unroll
      for (int i = 0; i < 12; ++i) wq[i] = wp[6 + i];
#pragma unroll
      for (int i = 0; i < 12; ++i)
        asm volatile("" : "+v"(wq[i].x), "+v"(wq[i].y), "+v"(wq[i].z), "+v"(wq[i].w));
    }
    float bR1 = 0, bZ1 = 0, bN1x = 0, bN1h = 0, hv1 = 0;
    if (wr) {
      bR1 = bih1[unit] + bhh1[unit];
      bZ1 = bih1[H_N + unit] + bhh1[H_N + unit];
      bN1x = bih1[2 * H_N + unit]; bN1h = bhh1[2 * H_N + unit];
      hv1 = hx[(size_t)(B_N + gbi) * H_N + unit];
    }

    for (int t = 0; t < T_N; ++t) {
      const ull* s1 = h1u + (size_t)S8(t - 1) * 8192 + (size_t)(8 * g) * 128;
      const ull e1 = T8(t - 1) ? M : 0ULL;
      const ull* s0 = h0u + (size_t)S8(t) * 8192 + (size_t)(8 * g) * 128;
      const ull e0 = T8(t) ? M : 0ULL;
      ull v1[2], v0[2];
      bool k1[2] = {false, false};
      bool k0[2] = {false, false};
#pragma unroll
      for (int e = 0; e < 2; ++e) {
        v1[e] = __hip_atomic_load(s1 + e * 512 + tid, __ATOMIC_RELAXED, __HIP_MEMORY_SCOPE_AGENT);
        v0[e] = __hip_atomic_load(s0 + e * 512 + tid, __ATOMIC_RELAXED, __HIP_MEMORY_SCOPE_AGENT);
      }
      POLL2(v1, k1, s1, e1)
#pragma unroll
      for (int e = 0; e < 2; ++e) sh1q[e * 512 + tid] = v1[e];
      POLL2(v0, k0, s0, e0)
#pragma unroll
      for (int e = 0; e < 2; ++e) shq[e * 512 + tid] = v0[e];
      __syncthreads();

      // B compute: x = h0_t, h = h1_{t-1}; 384 dot2/thread
      float aB[4][8];
#pragma unroll
      for (int q = 0; q < 4; ++q)
#pragma unroll
        for (int b8 = 0; b8 < 8; ++b8) aB[q][b8] = 0.f;
      const uint4* xp = (const uint4*)shq;
      const uint4* hp = (const uint4*)sh1q;
#pragma unroll
      for (int b8 = 0; b8 < 8; ++b8) {
        uint4 xc[2], hc[2];
        xc[0] = xp[b8 * 64 + s];      xc[1] = xp[b8 * 64 + s + 32];
        hc[0] = hp[b8 * 64 + s];      hc[1] = hp[b8 * 64 + s + 32];
        float a0 = aB[0][b8], a1 = aB[1][b8], a2 = aB[2][b8], a3 = aB[3][b8];
#pragma unroll
        for (int c = 0; c < 2; ++c) {
          D4Q(a0, wq[0 + c], xc[c]);  D4Q(a0, wq[6 + c],  hc[c]);
          D4Q(a1, wq[2 + c], xc[c]);  D4Q(a1, wq[8 + c],  hc[c]);
          D4Q(a2, wq[4 + c], xc[c]);
          D4Q(a3, wq[10 + c], hc[c]);
        }
        aB[0][b8] = a0; aB[1][b8] = a1; aB[2][b8] = a2; aB[3][b8] = a3;
      }
      float rB[4];
      rscat8w<4>(aB, rB, s);
      if (wr) {
        float r = sigm_(rB[0] + bR1);
        float z = sigm_(rB[1] + bZ1);
        float n = tanhf_(rB[2] + bN1x + r * (rB[3] + bN1h));
        float hy = n + z * (hv1 - n); hv1 = hy;
        pk[bb * 16 + u] = __builtin_bit_cast(unsigned short, (f16)hy);
      }
      __syncthreads();

      if (tid < 32) {    // tagged h1_t -> slot S8(t)
        ull v = ((const ull*)pk)[tid];
        v = (v & ~M) | (T8(t) ? M : 0ULL);
        ull* dp = (ull*)h1x + (size_t)S8(t) * 8192
                + (size_t)(8 * g + (tid >> 2)) * 128 + 4 * j + (tid & 3);
        __hip_atomic_store(dp, v, __ATOMIC_RELAXED, __HIP_MEMORY_SCOPE_AGENT);
      } else if (tid < 64) {  // fp32 out row t
        const int l = tid - 32;
        ull v = ((const ull*)pk)[l];
        f16x2 p0 = bch2((unsigned int)v), p1 = bch2((unsigned int)(v >> 32));
        float4 o = {(float)p0.x, (float)p0.y, (float)p1.x, (float)p1.y};
        float* op = out + ((size_t)t * B_N + 8 * g + (l >> 2)) * H_N + 16 * j + 4 * (l & 3);
        *(float4*)op = o;
        if (t == T_N - 1)
          *(float4*)(hT + (size_t)(B_N + 8 * g + (l >> 2)) * H_N + 16 * j + 4 * (l & 3)) = o;
      }
    }
  }
}

// ---------------------------------------------------------------------------
extern "C" void kernel_launch(void* const* d_in, const int* in_sizes, int n_in,
                              void* d_out, int out_size, void* d_ws, size_t ws_size,
                              hipStream_t stream)
{
  const float* x    = (const float*)d_in[0];
  const float* hx   = (const float*)d_in[1];
  const float* wih0 = (const float*)d_in[2];
  const float* whh0 = (const float*)d_in[3];
  const float* bih0 = (const float*)d_in[4];
  const float* bhh0 = (const float*)d_in[5];
  const float* wih1 = (const float*)d_in[6];
  const float* whh1 = (const float*)d_in[7];
  const float* bih1 = (const float*)d_in[8];
  const float* bhh1 = (const float*)d_in[9];
  float* out = (float*)d_out;            // [T*B*H] output, then [L*B*H] hT

  // workspace: gx | h0x 8*[B*H] f16 | h1x 8*[B*H] f16 | wbuf
  float* gxb = (float*)d_ws;
  f16*   h0x = (f16*)(gxb + (size_t)T_N * B_N * G3);
  f16*   h1x = h0x + 8 * B_N * H_N;
  uint4* wbuf = (uint4*)(h1x + 8 * B_N * H_N);   // 32*512*18 uint4 = 4.5 MB

  pack_h_init<<<128, 256, 0, stream>>>(hx, h0x, h1x);
  conv_w<<<(32 * 512 * 18) / 256, 256, 0, stream>>>(whh0, wih1, whh1, wbuf);

  dim3 gg(G3 / 64, (T_N * B_N) / 64);
  gemm_nt<<<gg, 256, 0, stream>>>(x, wih0, bih0, gxb, T_N * B_N, G3, I_N);

  gru_split<<<512, 512, 0, stream>>>(gxb, hx, wbuf,
                                     bih1, bhh0, bhh1,
                                     out, out + (size_t)T_N * B_N * H_N,
                                     h0x, h1x);
}